// Round 1
// baseline (168.806 us; speedup 1.0000x reference)
//
#include <hip/hip_runtime.h>
#include <math.h>

// TM-score: S=1024 samples, L=4096 residues, 3D fp32 coords.
// One block per sample. Phase 1: streaming sums -> 3x3 covariance.
// Thread 0: Horn quaternion Kabsch (4x4 Jacobi eigen, fp64).
// Phase 2: apply rotation, accumulate TM terms.

#define NS  1024
#define NL  4096
#define TPB 256
#define RPT (NL / TPB)   // 16

__device__ __forceinline__ float waveReduceSum(float v) {
    #pragma unroll
    for (int off = 32; off > 0; off >>= 1)
        v += __shfl_down(v, off, 64);
    return v;
}

__global__ __launch_bounds__(TPB) void tmscore_kernel(
    const float* __restrict__ pred,   // [S, L, 3]
    const float* __restrict__ tru,    // [L, 3]
    const int*   __restrict__ mask,   // [L]
    float*       __restrict__ out)    // [S]
{
    const int s    = blockIdx.x;
    const int tid  = threadIdx.x;
    const int wave = tid >> 6;
    const int lane = tid & 63;

    const float* ps = pred + (size_t)s * NL * 3;

    // acc: [0]=Lt, [1..3]=St, [4..6]=Sp, [7..15]=C[i][j] = sum w*p_i*t_j
    float acc[16];
    #pragma unroll
    for (int i = 0; i < 16; ++i) acc[i] = 0.f;

    #pragma unroll
    for (int k = 0; k < RPT; ++k) {
        const int l = tid + k * TPB;
        const float w  = mask[l] ? 1.0f : 0.0f;
        const float t0 = tru[l*3+0], t1 = tru[l*3+1], t2 = tru[l*3+2];
        const float p0 = ps[l*3+0],  p1 = ps[l*3+1],  p2 = ps[l*3+2];
        acc[0] += w;
        acc[1] += w*t0; acc[2] += w*t1; acc[3] += w*t2;
        const float wp0 = w*p0, wp1 = w*p1, wp2 = w*p2;
        acc[4] += wp0; acc[5] += wp1; acc[6] += wp2;
        acc[7]  += wp0*t0; acc[8]  += wp0*t1; acc[9]  += wp0*t2;
        acc[10] += wp1*t0; acc[11] += wp1*t1; acc[12] += wp1*t2;
        acc[13] += wp2*t0; acc[14] += wp2*t1; acc[15] += wp2*t2;
    }

    __shared__ float sred[4][16];
    __shared__ float bc[17];

    #pragma unroll
    for (int i = 0; i < 16; ++i) {
        float r = waveReduceSum(acc[i]);
        if (lane == 0) sred[wave][i] = r;
    }
    __syncthreads();

    if (tid == 0) {
        double S[16];
        for (int i = 0; i < 16; ++i)
            S[i] = (double)sred[0][i] + (double)sred[1][i]
                 + (double)sred[2][i] + (double)sred[3][i];
        const double Lt    = S[0];
        const double invLt = 1.0 / Lt;
        const double tmx = S[1]*invLt, tmy = S[2]*invLt, tmz = S[3]*invLt;
        const double pmx = S[4]*invLt, pmy = S[5]*invLt, pmz = S[6]*invLt;

        // H[i][j] = C[i][j] - Sp[i]*St[j]/Lt   (centered weighted covariance)
        double H[3][3];
        const double Sp[3] = {S[4], S[5], S[6]};
        const double St[3] = {S[1], S[2], S[3]};
        for (int i = 0; i < 3; ++i)
            for (int j = 0; j < 3; ++j)
                H[i][j] = S[7 + i*3 + j] - Sp[i]*St[j]*invLt;

        // Horn's 4x4 (pred -> true). Max eigenvector = optimal proper rotation.
        const double Sxx=H[0][0], Sxy=H[0][1], Sxz=H[0][2];
        const double Syx=H[1][0], Syy=H[1][1], Syz=H[1][2];
        const double Szx=H[2][0], Szy=H[2][1], Szz=H[2][2];
        double A[4][4] = {
          { Sxx+Syy+Szz, Syz-Szy,      Szx-Sxz,      Sxy-Syx      },
          { Syz-Szy,     Sxx-Syy-Szz,  Sxy+Syx,      Szx+Sxz      },
          { Szx-Sxz,     Sxy+Syx,      Syy-Sxx-Szz,  Syz+Szy      },
          { Sxy-Syx,     Szx+Sxz,      Syz+Szy,      Szz-Sxx-Syy  }
        };
        double V[4][4] = {{1,0,0,0},{0,1,0,0},{0,0,1,0},{0,0,0,1}};

        for (int sweep = 0; sweep < 10; ++sweep) {
            for (int p = 0; p < 3; ++p) for (int q = p+1; q < 4; ++q) {
                const double apq = A[p][q];
                if (fabs(apq) < 1e-300) continue;
                const double tau = (A[q][q] - A[p][p]) / (2.0 * apq);
                const double tt  = (tau >= 0.0 ? 1.0 : -1.0)
                                   / (fabs(tau) + sqrt(1.0 + tau*tau));
                const double cc  = 1.0 / sqrt(1.0 + tt*tt);
                const double sn  = tt * cc;
                for (int k = 0; k < 4; ++k) {           // A <- A*J
                    const double akp = A[k][p], akq = A[k][q];
                    A[k][p] = cc*akp - sn*akq;
                    A[k][q] = sn*akp + cc*akq;
                }
                for (int k = 0; k < 4; ++k) {           // A <- J^T*A
                    const double apk = A[p][k], aqk = A[q][k];
                    A[p][k] = cc*apk - sn*aqk;
                    A[q][k] = sn*apk + cc*aqk;
                }
                for (int k = 0; k < 4; ++k) {           // V <- V*J
                    const double vkp = V[k][p], vkq = V[k][q];
                    V[k][p] = cc*vkp - sn*vkq;
                    V[k][q] = sn*vkp + cc*vkq;
                }
            }
        }
        int im = 0;
        for (int i = 1; i < 4; ++i) if (A[i][i] > A[im][im]) im = i;
        const double q0 = V[0][im], qx = V[1][im], qy = V[2][im], qz = V[3][im];

        const double R00 = q0*q0+qx*qx-qy*qy-qz*qz;
        const double R01 = 2.0*(qx*qy - q0*qz);
        const double R02 = 2.0*(qx*qz + q0*qy);
        const double R10 = 2.0*(qy*qx + q0*qz);
        const double R11 = q0*q0-qx*qx+qy*qy-qz*qz;
        const double R12 = 2.0*(qy*qz - q0*qx);
        const double R20 = 2.0*(qz*qx - q0*qy);
        const double R21 = 2.0*(qz*qy + q0*qx);
        const double R22 = q0*q0-qx*qx-qy*qy+qz*qz;

        double d0 = (Lt <= 15.0) ? 0.5 : (1.24 * cbrt(Lt - 15.0) - 1.8);
        if (d0 < 0.5) d0 = 0.5;
        const double inv_d0sq = 1.0 / (d0 * d0);

        bc[0]=(float)R00; bc[1]=(float)R01; bc[2]=(float)R02;
        bc[3]=(float)R10; bc[4]=(float)R11; bc[5]=(float)R12;
        bc[6]=(float)R20; bc[7]=(float)R21; bc[8]=(float)R22;
        bc[9]=(float)pmx; bc[10]=(float)pmy; bc[11]=(float)pmz;
        bc[12]=(float)tmx; bc[13]=(float)tmy; bc[14]=(float)tmz;
        bc[15]=(float)inv_d0sq; bc[16]=(float)invLt;
    }
    __syncthreads();

    const float R00=bc[0], R01=bc[1], R02=bc[2];
    const float R10=bc[3], R11=bc[4], R12=bc[5];
    const float R20=bc[6], R21=bc[7], R22=bc[8];
    const float pmx=bc[9], pmy=bc[10], pmz=bc[11];
    const float tmx=bc[12], tmy=bc[13], tmz=bc[14];
    const float inv_d0sq = bc[15], invLt = bc[16];

    float tacc = 0.f;
    #pragma unroll
    for (int k = 0; k < RPT; ++k) {
        const int l = tid + k * TPB;
        const float w  = mask[l] ? 1.0f : 0.0f;
        const float t0 = tru[l*3+0], t1 = tru[l*3+1], t2 = tru[l*3+2];
        const float u0 = ps[l*3+0] - pmx;
        const float u1 = ps[l*3+1] - pmy;
        const float u2 = ps[l*3+2] - pmz;
        const float a0 = R00*u0 + R01*u1 + R02*u2 + tmx - t0;
        const float a1 = R10*u0 + R11*u1 + R12*u2 + tmy - t1;
        const float a2 = R20*u0 + R21*u1 + R22*u2 + tmz - t2;
        const float dsq = a0*a0 + a1*a1 + a2*a2;
        tacc += w / (1.0f + dsq * inv_d0sq);
    }
    float r = waveReduceSum(tacc);
    if (lane == 0) sred[wave][0] = r;
    __syncthreads();
    if (tid == 0)
        out[s] = (sred[0][0] + sred[1][0] + sred[2][0] + sred[3][0]) * invLt;
}

extern "C" void kernel_launch(void* const* d_in, const int* in_sizes, int n_in,
                              void* d_out, int out_size, void* d_ws, size_t ws_size,
                              hipStream_t stream) {
    const float* pred = (const float*)d_in[0];
    const float* tru  = (const float*)d_in[1];
    const int*   mask = (const int*)d_in[2];
    float* out = (float*)d_out;
    tmscore_kernel<<<NS, TPB, 0, stream>>>(pred, tru, mask, out);
}

// Round 2
// 128.015 us; speedup vs baseline: 1.3186x; 1.3186x over previous
//
#include <hip/hip_runtime.h>
#include <math.h>

// TM-score pipeline: S=1024 samples, L=4096 residues, fp32.
// K1: per-(sample,chunk) covariance partial sums   [4096 blocks x 256]
// K2: per-sample fp64 Horn-quaternion Kabsch       [1024 threads]
// K3: apply rotation + TM partial sums             [4096 blocks x 256]
// K4: final 4-way sum per sample                   [1024 threads]

#define NS   1024
#define NL   4096
#define SPL  4            // chunks per sample for K1/K3
#define TPB  256
#define RES_PER_THREAD 4  // (NL/SPL)/TPB

// ws layout (floats):
//   wsA [NS][SPL][16]  : partial sums      (K1 -> K2)   65536 floats
//   wsB [NS][20]       : R9,pm3,tm3,invd0sq,invLt,pad  (K2 -> K3) 20480 floats
//   wsC [NS][SPL]      : TM partials       (K3 -> K4)    4096 floats
#define WSA_OFF 0
#define WSB_OFF 65536
#define WSC_OFF (65536 + 20480)

__device__ __forceinline__ float waveReduceSum(float v) {
    #pragma unroll
    for (int off = 32; off > 0; off >>= 1)
        v += __shfl_down(v, off, 64);
    return v;
}

// ---------------- K1: covariance partial sums ----------------
__global__ __launch_bounds__(TPB) void k1_cov(
    const float* __restrict__ pred, const float* __restrict__ tru,
    const int* __restrict__ mask, float* __restrict__ ws)
{
    const int s   = blockIdx.x >> 2;
    const int c   = blockIdx.x & 3;
    const int tid = threadIdx.x;
    const int wave = tid >> 6, lane = tid & 63;
    const int rbase = c * (NL / SPL) + tid * RES_PER_THREAD;

    const float4* pp = (const float4*)(pred + (size_t)s * NL * 3 + (size_t)rbase * 3);
    const float4* tp = (const float4*)(tru + (size_t)rbase * 3);
    const int4    mi = *(const int4*)(mask + rbase);

    const float4 q0 = pp[0], q1 = pp[1], q2 = pp[2];
    const float4 u0 = tp[0], u1 = tp[1], u2 = tp[2];

    float px[4] = {q0.x, q0.w, q1.z, q2.y};
    float py[4] = {q0.y, q1.x, q1.w, q2.z};
    float pz[4] = {q0.z, q1.y, q2.x, q2.w};
    float tx[4] = {u0.x, u0.w, u1.z, u2.y};
    float ty[4] = {u0.y, u1.x, u1.w, u2.z};
    float tz[4] = {u0.z, u1.y, u2.x, u2.w};
    float wm[4] = {mi.x ? 1.f : 0.f, mi.y ? 1.f : 0.f, mi.z ? 1.f : 0.f, mi.w ? 1.f : 0.f};

    // acc: [0]=Lt [1..3]=St [4..6]=Sp [7..15]=C[i][j]=sum w*p_i*t_j
    float acc[16];
    #pragma unroll
    for (int i = 0; i < 16; ++i) acc[i] = 0.f;
    #pragma unroll
    for (int r = 0; r < 4; ++r) {
        const float w = wm[r];
        const float wpx = w * px[r], wpy = w * py[r], wpz = w * pz[r];
        acc[0] += w;
        acc[1] += w * tx[r]; acc[2] += w * ty[r]; acc[3] += w * tz[r];
        acc[4] += wpx; acc[5] += wpy; acc[6] += wpz;
        acc[7]  += wpx * tx[r]; acc[8]  += wpx * ty[r]; acc[9]  += wpx * tz[r];
        acc[10] += wpy * tx[r]; acc[11] += wpy * ty[r]; acc[12] += wpy * tz[r];
        acc[13] += wpz * tx[r]; acc[14] += wpz * ty[r]; acc[15] += wpz * tz[r];
    }

    __shared__ float sred[4][16];
    #pragma unroll
    for (int i = 0; i < 16; ++i) {
        float r = waveReduceSum(acc[i]);
        if (lane == 0) sred[wave][i] = r;
    }
    __syncthreads();
    if (tid < 16) {
        ws[WSA_OFF + (size_t)blockIdx.x * 16 + tid] =
            sred[0][tid] + sred[1][tid] + sred[2][tid] + sred[3][tid];
    }
}

// ---------------- K2: per-sample Kabsch (Horn quaternion, fp64) -------------
__global__ __launch_bounds__(64) void k2_kabsch(float* __restrict__ ws)
{
    const int sid = blockIdx.x * 64 + threadIdx.x;
    if (sid >= NS) return;

    double S[16];
    #pragma unroll
    for (int i = 0; i < 16; ++i) S[i] = 0.0;
    const float* base = ws + WSA_OFF + (size_t)sid * SPL * 16;
    #pragma unroll
    for (int c = 0; c < SPL; ++c)
        #pragma unroll
        for (int i = 0; i < 16; ++i)
            S[i] += (double)base[c * 16 + i];

    const double Lt = S[0], invLt = 1.0 / Lt;
    const double tmx = S[1]*invLt, tmy = S[2]*invLt, tmz = S[3]*invLt;
    const double pmx = S[4]*invLt, pmy = S[5]*invLt, pmz = S[6]*invLt;

    double H[3][3];
    const double Sp[3] = {S[4], S[5], S[6]};
    const double St[3] = {S[1], S[2], S[3]};
    #pragma unroll
    for (int i = 0; i < 3; ++i)
        #pragma unroll
        for (int j = 0; j < 3; ++j)
            H[i][j] = S[7 + i*3 + j] - Sp[i]*St[j]*invLt;

    const double Sxx=H[0][0], Sxy=H[0][1], Sxz=H[0][2];
    const double Syx=H[1][0], Syy=H[1][1], Syz=H[1][2];
    const double Szx=H[2][0], Szy=H[2][1], Szz=H[2][2];
    double A[4][4] = {
      { Sxx+Syy+Szz, Syz-Szy,      Szx-Sxz,      Sxy-Syx      },
      { Syz-Szy,     Sxx-Syy-Szz,  Sxy+Syx,      Szx+Sxz      },
      { Szx-Sxz,     Sxy+Syx,      Syy-Sxx-Szz,  Syz+Szy      },
      { Sxy-Syx,     Szx+Sxz,      Syz+Szy,      Szz-Sxx-Syy  }
    };
    double V[4][4] = {{1,0,0,0},{0,1,0,0},{0,0,1,0},{0,0,0,1}};

    for (int sweep = 0; sweep < 8; ++sweep) {
        for (int p = 0; p < 3; ++p) for (int q = p+1; q < 4; ++q) {
            const double apq = A[p][q];
            if (fabs(apq) < 1e-300) continue;
            const double tau = (A[q][q] - A[p][p]) / (2.0 * apq);
            const double tt  = (tau >= 0.0 ? 1.0 : -1.0)
                               / (fabs(tau) + sqrt(1.0 + tau*tau));
            const double cc  = 1.0 / sqrt(1.0 + tt*tt);
            const double sn  = tt * cc;
            #pragma unroll
            for (int k = 0; k < 4; ++k) {
                const double akp = A[k][p], akq = A[k][q];
                A[k][p] = cc*akp - sn*akq;
                A[k][q] = sn*akp + cc*akq;
            }
            #pragma unroll
            for (int k = 0; k < 4; ++k) {
                const double apk = A[p][k], aqk = A[q][k];
                A[p][k] = cc*apk - sn*aqk;
                A[q][k] = sn*apk + cc*aqk;
            }
            #pragma unroll
            for (int k = 0; k < 4; ++k) {
                const double vkp = V[k][p], vkq = V[k][q];
                V[k][p] = cc*vkp - sn*vkq;
                V[k][q] = sn*vkp + cc*vkq;
            }
        }
    }
    int im = 0;
    #pragma unroll
    for (int i = 1; i < 4; ++i) if (A[i][i] > A[im][im]) im = i;
    const double q0 = V[0][im], qx = V[1][im], qy = V[2][im], qz = V[3][im];

    const double R00 = q0*q0+qx*qx-qy*qy-qz*qz;
    const double R01 = 2.0*(qx*qy - q0*qz);
    const double R02 = 2.0*(qx*qz + q0*qy);
    const double R10 = 2.0*(qy*qx + q0*qz);
    const double R11 = q0*q0-qx*qx+qy*qy-qz*qz;
    const double R12 = 2.0*(qy*qz - q0*qx);
    const double R20 = 2.0*(qz*qx - q0*qy);
    const double R21 = 2.0*(qz*qy + q0*qx);
    const double R22 = q0*q0-qx*qx-qy*qy+qz*qz;

    double d0 = (Lt <= 15.0) ? 0.5 : (1.24 * cbrt(Lt - 15.0) - 1.8);
    if (d0 < 0.5) d0 = 0.5;
    const double inv_d0sq = 1.0 / (d0 * d0);

    float* o = ws + WSB_OFF + (size_t)sid * 20;
    o[0]=(float)R00; o[1]=(float)R01; o[2]=(float)R02;
    o[3]=(float)R10; o[4]=(float)R11; o[5]=(float)R12;
    o[6]=(float)R20; o[7]=(float)R21; o[8]=(float)R22;
    o[9]=(float)pmx; o[10]=(float)pmy; o[11]=(float)pmz;
    o[12]=(float)tmx; o[13]=(float)tmy; o[14]=(float)tmz;
    o[15]=(float)inv_d0sq; o[16]=(float)invLt;
    o[17]=0.f; o[18]=0.f; o[19]=0.f;
}

// ---------------- K3: apply rotation + TM partials ----------------
__global__ __launch_bounds__(TPB) void k3_score(
    const float* __restrict__ pred, const float* __restrict__ tru,
    const int* __restrict__ mask, float* __restrict__ ws)
{
    const int s   = blockIdx.x >> 2;
    const int c   = blockIdx.x & 3;
    const int tid = threadIdx.x;
    const int wave = tid >> 6, lane = tid & 63;
    const int rbase = c * (NL / SPL) + tid * RES_PER_THREAD;

    const float4* bp = (const float4*)(ws + WSB_OFF + (size_t)s * 20);
    const float4 b0 = bp[0], b1 = bp[1], b2 = bp[2], b3 = bp[3], b4 = bp[4];
    const float R00=b0.x, R01=b0.y, R02=b0.z, R10=b0.w;
    const float R11=b1.x, R12=b1.y, R20=b1.z, R21=b1.w;
    const float R22=b2.x, pmx=b2.y, pmy=b2.z, pmz=b2.w;
    const float tmx=b3.x, tmy=b3.y, tmz=b3.z, inv_d0sq=b3.w;
    const float invLt=b4.x;

    const float4* pp = (const float4*)(pred + (size_t)s * NL * 3 + (size_t)rbase * 3);
    const float4* tp = (const float4*)(tru + (size_t)rbase * 3);
    const int4    mi = *(const int4*)(mask + rbase);

    const float4 q0 = pp[0], q1 = pp[1], q2 = pp[2];
    const float4 u0 = tp[0], u1 = tp[1], u2 = tp[2];

    float px[4] = {q0.x, q0.w, q1.z, q2.y};
    float py[4] = {q0.y, q1.x, q1.w, q2.z};
    float pz[4] = {q0.z, q1.y, q2.x, q2.w};
    float tx[4] = {u0.x, u0.w, u1.z, u2.y};
    float ty[4] = {u0.y, u1.x, u1.w, u2.z};
    float tz[4] = {u0.z, u1.y, u2.x, u2.w};
    float wm[4] = {mi.x ? 1.f : 0.f, mi.y ? 1.f : 0.f, mi.z ? 1.f : 0.f, mi.w ? 1.f : 0.f};

    float tacc = 0.f;
    #pragma unroll
    for (int r = 0; r < 4; ++r) {
        const float vx = px[r] - pmx, vy = py[r] - pmy, vz = pz[r] - pmz;
        const float a0 = R00*vx + R01*vy + R02*vz + tmx - tx[r];
        const float a1 = R10*vx + R11*vy + R12*vz + tmy - ty[r];
        const float a2 = R20*vx + R21*vy + R22*vz + tmz - tz[r];
        const float dsq = a0*a0 + a1*a1 + a2*a2;
        tacc += wm[r] / (1.0f + dsq * inv_d0sq);
    }
    tacc *= invLt;

    __shared__ float sred[4];
    float r = waveReduceSum(tacc);
    if (lane == 0) sred[wave] = r;
    __syncthreads();
    if (tid == 0)
        ws[WSC_OFF + (size_t)blockIdx.x] = sred[0] + sred[1] + sred[2] + sred[3];
}

// ---------------- K4: final reduce ----------------
__global__ __launch_bounds__(TPB) void k4_final(const float* __restrict__ ws,
                                                float* __restrict__ out)
{
    const int s = blockIdx.x * TPB + threadIdx.x;
    if (s >= NS) return;
    const float4 v = *(const float4*)(ws + WSC_OFF + (size_t)s * SPL);
    out[s] = v.x + v.y + v.z + v.w;
}

extern "C" void kernel_launch(void* const* d_in, const int* in_sizes, int n_in,
                              void* d_out, int out_size, void* d_ws, size_t ws_size,
                              hipStream_t stream) {
    const float* pred = (const float*)d_in[0];
    const float* tru  = (const float*)d_in[1];
    const int*   mask = (const int*)d_in[2];
    float* out = (float*)d_out;
    float* ws  = (float*)d_ws;

    k1_cov   <<<NS * SPL, TPB, 0, stream>>>(pred, tru, mask, ws);
    k2_kabsch<<<(NS + 63) / 64, 64, 0, stream>>>(ws);
    k3_score <<<NS * SPL, TPB, 0, stream>>>(pred, tru, mask, ws);
    k4_final <<<(NS + TPB - 1) / TPB, TPB, 0, stream>>>(ws, out);
}

// Round 3
// 120.862 us; speedup vs baseline: 1.3967x; 1.0592x over previous
//
#include <hip/hip_runtime.h>
#include <math.h>

// TM-score pipeline: S=1024 samples, L=4096 residues, fp32.
// K1: per-sample covariance sums (1 block/sample)   [1024 blocks x 256]
// K2: per-sample Kabsch, fp64 H + fp32 Jacobi       [1024 threads]
// K3: apply rotation + TM sum -> out[s]             [1024 blocks x 256]

#define NS   1024
#define NL   4096
#define TPB  256
#define CHUNKS 4          // 4 chunks x 4 residues/thread = 16 res/thread

// ws layout (floats):
//   wsA [NS][16] : full-sample sums   (K1 -> K2)   16384 floats
//   wsB [NS][20] : R9,pm3,tm3,invd0sq,invLt,pad    (K2 -> K3)
#define WSA_OFF 0
#define WSB_OFF 16384

__device__ __forceinline__ float waveReduceSum(float v) {
    #pragma unroll
    for (int off = 32; off > 0; off >>= 1)
        v += __shfl_down(v, off, 64);
    return v;
}

// ---------------- K1: per-sample covariance sums ----------------
__global__ __launch_bounds__(TPB) void k1_cov(
    const float* __restrict__ pred, const float* __restrict__ tru,
    const int* __restrict__ mask, float* __restrict__ ws)
{
    const int s   = blockIdx.x;
    const int tid = threadIdx.x;
    const int wave = tid >> 6, lane = tid & 63;
    const float* ps = pred + (size_t)s * NL * 3;

    // acc: [0]=Lt [1..3]=St [4..6]=Sp [7..15]=C[i][j]=sum w*p_i*t_j
    float acc[16];
    #pragma unroll
    for (int i = 0; i < 16; ++i) acc[i] = 0.f;

    #pragma unroll
    for (int k = 0; k < CHUNKS; ++k) {
        const int rbase = k * (NL / CHUNKS) + tid * 4;
        const float4* pp = (const float4*)(ps + (size_t)rbase * 3);
        const float4* tp = (const float4*)(tru + (size_t)rbase * 3);
        const int4    mi = *(const int4*)(mask + rbase);
        const float4 q0 = pp[0], q1 = pp[1], q2 = pp[2];
        const float4 u0 = tp[0], u1 = tp[1], u2 = tp[2];

        const float px[4] = {q0.x, q0.w, q1.z, q2.y};
        const float py[4] = {q0.y, q1.x, q1.w, q2.z};
        const float pz[4] = {q0.z, q1.y, q2.x, q2.w};
        const float tx[4] = {u0.x, u0.w, u1.z, u2.y};
        const float ty[4] = {u0.y, u1.x, u1.w, u2.z};
        const float tz[4] = {u0.z, u1.y, u2.x, u2.w};
        const float wm[4] = {mi.x ? 1.f : 0.f, mi.y ? 1.f : 0.f,
                             mi.z ? 1.f : 0.f, mi.w ? 1.f : 0.f};

        #pragma unroll
        for (int r = 0; r < 4; ++r) {
            const float w = wm[r];
            const float wpx = w * px[r], wpy = w * py[r], wpz = w * pz[r];
            acc[0] += w;
            acc[1] += w * tx[r]; acc[2] += w * ty[r]; acc[3] += w * tz[r];
            acc[4] += wpx; acc[5] += wpy; acc[6] += wpz;
            acc[7]  += wpx * tx[r]; acc[8]  += wpx * ty[r]; acc[9]  += wpx * tz[r];
            acc[10] += wpy * tx[r]; acc[11] += wpy * ty[r]; acc[12] += wpy * tz[r];
            acc[13] += wpz * tx[r]; acc[14] += wpz * ty[r]; acc[15] += wpz * tz[r];
        }
    }

    __shared__ float sred[4][16];
    #pragma unroll
    for (int i = 0; i < 16; ++i) {
        float r = waveReduceSum(acc[i]);
        if (lane == 0) sred[wave][i] = r;
    }
    __syncthreads();
    if (tid < 16) {
        ws[WSA_OFF + (size_t)s * 16 + tid] =
            sred[0][tid] + sred[1][tid] + sred[2][tid] + sred[3][tid];
    }
}

// ------- K2: Kabsch. fp64 H assembly, fp32 Jacobi on scaled matrix -------
__global__ __launch_bounds__(TPB) void k2_kabsch(float* __restrict__ ws)
{
    const int sid = blockIdx.x * TPB + threadIdx.x;
    if (sid >= NS) return;

    const float* base = ws + WSA_OFF + (size_t)sid * 16;
    double S[16];
    #pragma unroll
    for (int i = 0; i < 16; ++i) S[i] = (double)base[i];

    const double Lt = S[0], invLt = 1.0 / Lt;
    const double tmx = S[1]*invLt, tmy = S[2]*invLt, tmz = S[3]*invLt;
    const double pmx = S[4]*invLt, pmy = S[5]*invLt, pmz = S[6]*invLt;

    // H[i][j]/Lt  (scaling H doesn't change the optimal rotation)
    float H[3][3];
    const double Sp[3] = {S[4], S[5], S[6]};
    const double St[3] = {S[1], S[2], S[3]};
    #pragma unroll
    for (int i = 0; i < 3; ++i)
        #pragma unroll
        for (int j = 0; j < 3; ++j)
            H[i][j] = (float)((S[7 + i*3 + j] - Sp[i]*St[j]*invLt) * invLt);

    const float Sxx=H[0][0], Sxy=H[0][1], Sxz=H[0][2];
    const float Syx=H[1][0], Syy=H[1][1], Syz=H[1][2];
    const float Szx=H[2][0], Szy=H[2][1], Szz=H[2][2];
    float A[4][4] = {
      { Sxx+Syy+Szz, Syz-Szy,      Szx-Sxz,      Sxy-Syx      },
      { Syz-Szy,     Sxx-Syy-Szz,  Sxy+Syx,      Szx+Sxz      },
      { Szx-Sxz,     Sxy+Syx,      Syy-Sxx-Szz,  Syz+Szy      },
      { Sxy-Syx,     Szx+Sxz,      Syz+Szy,      Szz-Sxx-Syy  }
    };
    float V[4][4] = {{1,0,0,0},{0,1,0,0},{0,0,1,0},{0,0,0,1}};

    for (int sweep = 0; sweep < 8; ++sweep) {
        for (int p = 0; p < 3; ++p) for (int q = p+1; q < 4; ++q) {
            const float apq = A[p][q];
            if (fabsf(apq) < 1e-30f) continue;
            const float tau = (A[q][q] - A[p][p]) / (2.0f * apq);
            const float tt  = (tau >= 0.0f ? 1.0f : -1.0f)
                              / (fabsf(tau) + sqrtf(1.0f + tau*tau));
            const float cc  = 1.0f / sqrtf(1.0f + tt*tt);
            const float sn  = tt * cc;
            #pragma unroll
            for (int k = 0; k < 4; ++k) {
                const float akp = A[k][p], akq = A[k][q];
                A[k][p] = cc*akp - sn*akq;
                A[k][q] = sn*akp + cc*akq;
            }
            #pragma unroll
            for (int k = 0; k < 4; ++k) {
                const float apk = A[p][k], aqk = A[q][k];
                A[p][k] = cc*apk - sn*aqk;
                A[q][k] = sn*apk + cc*aqk;
            }
            #pragma unroll
            for (int k = 0; k < 4; ++k) {
                const float vkp = V[k][p], vkq = V[k][q];
                V[k][p] = cc*vkp - sn*vkq;
                V[k][q] = sn*vkp + cc*vkq;
            }
        }
    }
    int im = 0;
    #pragma unroll
    for (int i = 1; i < 4; ++i) if (A[i][i] > A[im][im]) im = i;
    const float q0 = V[0][im], qx = V[1][im], qy = V[2][im], qz = V[3][im];

    const float R00 = q0*q0+qx*qx-qy*qy-qz*qz;
    const float R01 = 2.0f*(qx*qy - q0*qz);
    const float R02 = 2.0f*(qx*qz + q0*qy);
    const float R10 = 2.0f*(qy*qx + q0*qz);
    const float R11 = q0*q0-qx*qx+qy*qy-qz*qz;
    const float R12 = 2.0f*(qy*qz - q0*qx);
    const float R20 = 2.0f*(qz*qx - q0*qy);
    const float R21 = 2.0f*(qz*qy + q0*qx);
    const float R22 = q0*q0-qx*qx-qy*qy+qz*qz;

    double d0 = (Lt <= 15.0) ? 0.5 : (1.24 * cbrt(Lt - 15.0) - 1.8);
    if (d0 < 0.5) d0 = 0.5;
    const double inv_d0sq = 1.0 / (d0 * d0);

    float* o = ws + WSB_OFF + (size_t)sid * 20;
    o[0]=R00; o[1]=R01; o[2]=R02;
    o[3]=R10; o[4]=R11; o[5]=R12;
    o[6]=R20; o[7]=R21; o[8]=R22;
    o[9]=(float)pmx; o[10]=(float)pmy; o[11]=(float)pmz;
    o[12]=(float)tmx; o[13]=(float)tmy; o[14]=(float)tmz;
    o[15]=(float)inv_d0sq; o[16]=(float)invLt;
    o[17]=0.f; o[18]=0.f; o[19]=0.f;
}

// ---------------- K3: apply rotation + TM sum -> out ----------------
__global__ __launch_bounds__(TPB) void k3_score(
    const float* __restrict__ pred, const float* __restrict__ tru,
    const int* __restrict__ mask, const float* __restrict__ ws,
    float* __restrict__ out)
{
    const int s   = blockIdx.x;
    const int tid = threadIdx.x;
    const int wave = tid >> 6, lane = tid & 63;
    const float* ps = pred + (size_t)s * NL * 3;

    const float4* bp = (const float4*)(ws + WSB_OFF + (size_t)s * 20);
    const float4 b0 = bp[0], b1 = bp[1], b2 = bp[2], b3 = bp[3], b4 = bp[4];
    const float R00=b0.x, R01=b0.y, R02=b0.z, R10=b0.w;
    const float R11=b1.x, R12=b1.y, R20=b1.z, R21=b1.w;
    const float R22=b2.x, pmx=b2.y, pmy=b2.z, pmz=b2.w;
    const float tmx=b3.x, tmy=b3.y, tmz=b3.z, inv_d0sq=b3.w;
    const float invLt=b4.x;

    float tacc = 0.f;
    #pragma unroll
    for (int k = 0; k < CHUNKS; ++k) {
        const int rbase = k * (NL / CHUNKS) + tid * 4;
        const float4* pp = (const float4*)(ps + (size_t)rbase * 3);
        const float4* tp = (const float4*)(tru + (size_t)rbase * 3);
        const int4    mi = *(const int4*)(mask + rbase);
        const float4 q0 = pp[0], q1 = pp[1], q2 = pp[2];
        const float4 u0 = tp[0], u1 = tp[1], u2 = tp[2];

        const float px[4] = {q0.x, q0.w, q1.z, q2.y};
        const float py[4] = {q0.y, q1.x, q1.w, q2.z};
        const float pz[4] = {q0.z, q1.y, q2.x, q2.w};
        const float tx[4] = {u0.x, u0.w, u1.z, u2.y};
        const float ty[4] = {u0.y, u1.x, u1.w, u2.z};
        const float tz[4] = {u0.z, u1.y, u2.x, u2.w};
        const float wm[4] = {mi.x ? 1.f : 0.f, mi.y ? 1.f : 0.f,
                             mi.z ? 1.f : 0.f, mi.w ? 1.f : 0.f};

        #pragma unroll
        for (int r = 0; r < 4; ++r) {
            const float vx = px[r] - pmx, vy = py[r] - pmy, vz = pz[r] - pmz;
            const float a0 = R00*vx + R01*vy + R02*vz + tmx - tx[r];
            const float a1 = R10*vx + R11*vy + R12*vz + tmy - ty[r];
            const float a2 = R20*vx + R21*vy + R22*vz + tmz - tz[r];
            const float dsq = a0*a0 + a1*a1 + a2*a2;
            tacc += wm[r] * __builtin_amdgcn_rcpf(1.0f + dsq * inv_d0sq);
        }
    }
    tacc *= invLt;

    __shared__ float sred[4];
    float r = waveReduceSum(tacc);
    if (lane == 0) sred[wave] = r;
    __syncthreads();
    if (tid == 0)
        out[s] = sred[0] + sred[1] + sred[2] + sred[3];
}

extern "C" void kernel_launch(void* const* d_in, const int* in_sizes, int n_in,
                              void* d_out, int out_size, void* d_ws, size_t ws_size,
                              hipStream_t stream) {
    const float* pred = (const float*)d_in[0];
    const float* tru  = (const float*)d_in[1];
    const int*   mask = (const int*)d_in[2];
    float* out = (float*)d_out;
    float* ws  = (float*)d_ws;

    k1_cov   <<<NS, TPB, 0, stream>>>(pred, tru, mask, ws);
    k2_kabsch<<<(NS + TPB - 1) / TPB, TPB, 0, stream>>>(ws);
    k3_score <<<NS, TPB, 0, stream>>>(pred, tru, mask, ws, out);
}

// Round 4
// 99.139 us; speedup vs baseline: 1.7027x; 1.2191x over previous
//
#include <hip/hip_runtime.h>
#include <math.h>

// TM-score, single fused kernel. S=1024 samples, L=4096 residues, fp32.
// One block per sample, 256 threads, 16 residues/thread in 4 chunks.
// Phase 1: LDS-staged coalesced loads -> 18 covariance sums (block reduce).
// Solve:   every thread redundantly runs Theobald QCP (fp64 Newton on the
//          quartic char poly of the 4x4 Horn matrix; eigvec via adjugate).
// Phase 2: re-stage (L2/L3-warm) -> aligned distances -> TM sum -> out[s].

#define NS        1024
#define NL        4096
#define TPB       256
#define CHUNK_RES 1024
#define NCHUNK    4

__device__ __forceinline__ float waveReduceSum(float v) {
    #pragma unroll
    for (int off = 32; off > 0; off >>= 1)
        v += __shfl_down(v, off, 64);
    return v;
}

__device__ __forceinline__ double det3(const double B[4][4],
                                       int r0, int r1, int r2,
                                       int c0, int c1, int c2) {
    return B[r0][c0]*(B[r1][c1]*B[r2][c2] - B[r1][c2]*B[r2][c1])
         - B[r0][c1]*(B[r1][c0]*B[r2][c2] - B[r1][c2]*B[r2][c0])
         + B[r0][c2]*(B[r1][c0]*B[r2][c1] - B[r1][c1]*B[r2][c0]);
}

__global__ __launch_bounds__(TPB, 4) void tm_fused(
    const float* __restrict__ pred, const float* __restrict__ tru,
    const int* __restrict__ mask, float* __restrict__ out)
{
    const int s    = blockIdx.x;
    const int tid  = threadIdx.x;
    const int wave = tid >> 6, lane = tid & 63;
    const float* ps = pred + (size_t)s * NL * 3;

    __shared__ float ldsP[CHUNK_RES * 3];   // 12 KB
    __shared__ float ldsT[CHUNK_RES * 3];   // 12 KB
    __shared__ float sred[4][18];

    // acc: [0]=Lt [1..3]=St [4..6]=Sp [7..15]=C[i][j] [16]=Sum w|p|^2 [17]=Sum w|t|^2
    float acc[18];
    #pragma unroll
    for (int i = 0; i < 18; ++i) acc[i] = 0.f;

    // ---------------- Phase 1: covariance sums ----------------
    for (int k = 0; k < NCHUNK; ++k) {
        const float4* gp = (const float4*)(ps  + (size_t)k * CHUNK_RES * 3);
        const float4* gt = (const float4*)(tru + (size_t)k * CHUNK_RES * 3);
        float4* lp = (float4*)ldsP;
        float4* lt = (float4*)ldsT;
        #pragma unroll
        for (int j = 0; j < 3; ++j) {
            const int idx = wave * 192 + j * 64 + lane;   // coalesced 1KB/instr
            lp[idx] = gp[idx];
            lt[idx] = gt[idx];
        }
        __syncthreads();

        const float4* rp = (const float4*)&ldsP[tid * 12];
        const float4* rt = (const float4*)&ldsT[tid * 12];
        const float4 q0 = rp[0], q1 = rp[1], q2 = rp[2];
        const float4 u0 = rt[0], u1 = rt[1], u2 = rt[2];
        const int4   mi = *(const int4*)(mask + k * CHUNK_RES + tid * 4);

        const float px[4] = {q0.x, q0.w, q1.z, q2.y};
        const float py[4] = {q0.y, q1.x, q1.w, q2.z};
        const float pz[4] = {q0.z, q1.y, q2.x, q2.w};
        const float tx[4] = {u0.x, u0.w, u1.z, u2.y};
        const float ty[4] = {u0.y, u1.x, u1.w, u2.z};
        const float tz[4] = {u0.z, u1.y, u2.x, u2.w};
        const float wm[4] = {mi.x ? 1.f : 0.f, mi.y ? 1.f : 0.f,
                             mi.z ? 1.f : 0.f, mi.w ? 1.f : 0.f};

        #pragma unroll
        for (int r = 0; r < 4; ++r) {
            const float w = wm[r];
            const float wpx = w * px[r], wpy = w * py[r], wpz = w * pz[r];
            acc[0] += w;
            acc[1] += w * tx[r]; acc[2] += w * ty[r]; acc[3] += w * tz[r];
            acc[4] += wpx; acc[5] += wpy; acc[6] += wpz;
            acc[7]  += wpx * tx[r]; acc[8]  += wpx * ty[r]; acc[9]  += wpx * tz[r];
            acc[10] += wpy * tx[r]; acc[11] += wpy * ty[r]; acc[12] += wpy * tz[r];
            acc[13] += wpz * tx[r]; acc[14] += wpz * ty[r]; acc[15] += wpz * tz[r];
            acc[16] += wpx * px[r] + wpy * py[r] + wpz * pz[r];
            acc[17] += w * (tx[r]*tx[r] + ty[r]*ty[r] + tz[r]*tz[r]);
        }
        __syncthreads();   // before next chunk overwrites LDS
    }

    #pragma unroll
    for (int i = 0; i < 18; ++i) {
        float r = waveReduceSum(acc[i]);
        if (lane == 0) sred[wave][i] = r;
    }
    __syncthreads();

    // ---------------- QCP solve (all threads, identical data) ----------------
    double S[18];
    #pragma unroll
    for (int i = 0; i < 18; ++i)
        S[i] = (double)sred[0][i] + (double)sred[1][i]
             + (double)sred[2][i] + (double)sred[3][i];

    const double Lt = S[0], invLt = 1.0 / Lt;
    const double tmxd = S[1]*invLt, tmyd = S[2]*invLt, tmzd = S[3]*invLt;
    const double pmxd = S[4]*invLt, pmyd = S[5]*invLt, pmzd = S[6]*invLt;

    // scaled centered covariance HA = (C - Sp St^T / Lt) / Lt ; scaled Gram traces
    double HA[3][3];
    const double Sp[3] = {S[4], S[5], S[6]};
    const double St[3] = {S[1], S[2], S[3]};
    #pragma unroll
    for (int i = 0; i < 3; ++i)
        #pragma unroll
        for (int j = 0; j < 3; ++j)
            HA[i][j] = (S[7 + i*3 + j] - Sp[i]*St[j]*invLt) * invLt;
    const double gA = (S[16] - (Sp[0]*Sp[0]+Sp[1]*Sp[1]+Sp[2]*Sp[2])*invLt) * invLt;
    const double gB = (S[17] - (St[0]*St[0]+St[1]*St[1]+St[2]*St[2])*invLt) * invLt;

    const double Sxx=HA[0][0], Sxy=HA[0][1], Sxz=HA[0][2];
    const double Syx=HA[1][0], Syy=HA[1][1], Syz=HA[1][2];
    const double Szx=HA[2][0], Szy=HA[2][1], Szz=HA[2][2];
    double K[4][4] = {
      { Sxx+Syy+Szz, Syz-Szy,      Szx-Sxz,      Sxy-Syx      },
      { Syz-Szy,     Sxx-Syy-Szz,  Sxy+Syx,      Szx+Sxz      },
      { Szx-Sxz,     Sxy+Syx,      Syy-Sxx-Szz,  Syz+Szy      },
      { Sxy-Syx,     Szx+Sxz,      Syz+Szy,      Szz-Sxx-Syy  }
    };

    // char poly det(lam I - K) = lam^4 + E2 lam^2 - E3 lam + E4   (tr K = 0)
    double E2 = 0.0;
    #pragma unroll
    for (int i = 0; i < 4; ++i)
        #pragma unroll
        for (int j = 0; j < 4; ++j)
            if (j > i) E2 += K[i][i]*K[j][j] - K[i][j]*K[i][j];
    const double E3 = det3(K,1,2,3, 1,2,3) + det3(K,0,2,3, 0,2,3)
                    + det3(K,0,1,3, 0,1,3) + det3(K,0,1,2, 0,1,2);
    const double E4 = K[0][0]*det3(K,1,2,3, 1,2,3) - K[0][1]*det3(K,1,2,3, 0,2,3)
                    + K[0][2]*det3(K,1,2,3, 0,1,3) - K[0][3]*det3(K,1,2,3, 0,1,2);

    double lam = 0.5 * (gA + gB);          // upper bound on lambda_max
    #pragma unroll
    for (int it = 0; it < 8; ++it) {
        const double l2 = lam * lam;
        const double P  = ((l2 + E2) * lam - E3) * lam + E4;
        const double Pd = (4.0 * l2 + 2.0 * E2) * lam - E3;
        if (fabs(Pd) < 1e-300) break;
        lam -= P / Pd;
    }

    // eigenvector = best row of cofactor matrix of B = K - lam I
    #pragma unroll
    for (int i = 0; i < 4; ++i) K[i][i] -= lam;
    double best[4] = {1.0, 0.0, 0.0, 0.0};
    double bestn = -1.0;
    #pragma unroll
    for (int r = 0; r < 4; ++r) {
        int ri[3]; int t = 0;
        #pragma unroll
        for (int i = 0; i < 4; ++i) if (i != r) ri[t++] = i;
        double v[4];
        #pragma unroll
        for (int c = 0; c < 4; ++c) {
            int cj[3]; t = 0;
            #pragma unroll
            for (int j = 0; j < 4; ++j) if (j != c) cj[t++] = j;
            const double d = det3(K, ri[0],ri[1],ri[2], cj[0],cj[1],cj[2]);
            v[c] = ((r + c) & 1) ? -d : d;
        }
        const double n = v[0]*v[0]+v[1]*v[1]+v[2]*v[2]+v[3]*v[3];
        if (n > bestn) { bestn = n; best[0]=v[0]; best[1]=v[1]; best[2]=v[2]; best[3]=v[3]; }
    }
    const double qn = 1.0 / sqrt(bestn);
    const double q0d = best[0]*qn, qxd = best[1]*qn, qyd = best[2]*qn, qzd = best[3]*qn;

    const float R00 = (float)(q0d*q0d+qxd*qxd-qyd*qyd-qzd*qzd);
    const float R01 = (float)(2.0*(qxd*qyd - q0d*qzd));
    const float R02 = (float)(2.0*(qxd*qzd + q0d*qyd));
    const float R10 = (float)(2.0*(qyd*qxd + q0d*qzd));
    const float R11 = (float)(q0d*q0d-qxd*qxd+qyd*qyd-qzd*qzd);
    const float R12 = (float)(2.0*(qyd*qzd - q0d*qxd));
    const float R20 = (float)(2.0*(qzd*qxd - q0d*qyd));
    const float R21 = (float)(2.0*(qzd*qyd + q0d*qxd));
    const float R22 = (float)(q0d*q0d-qxd*qxd-qyd*qyd+qzd*qzd);

    double d0 = (Lt <= 15.0) ? 0.5 : (1.24 * cbrt(Lt - 15.0) - 1.8);
    if (d0 < 0.5) d0 = 0.5;
    const float inv_d0sq = (float)(1.0 / (d0 * d0));
    const float invLtf   = (float)invLt;
    const float pmx = (float)pmxd, pmy = (float)pmyd, pmz = (float)pmzd;
    const float tmx = (float)tmxd, tmy = (float)tmyd, tmz = (float)tmzd;

    // ---------------- Phase 2: aligned distances -> TM ----------------
    float tacc = 0.f;
    for (int k = 0; k < NCHUNK; ++k) {
        const float4* gp = (const float4*)(ps  + (size_t)k * CHUNK_RES * 3);
        const float4* gt = (const float4*)(tru + (size_t)k * CHUNK_RES * 3);
        float4* lp = (float4*)ldsP;
        float4* lt = (float4*)ldsT;
        #pragma unroll
        for (int j = 0; j < 3; ++j) {
            const int idx = wave * 192 + j * 64 + lane;
            lp[idx] = gp[idx];
            lt[idx] = gt[idx];
        }
        __syncthreads();

        const float4* rp = (const float4*)&ldsP[tid * 12];
        const float4* rt = (const float4*)&ldsT[tid * 12];
        const float4 q0 = rp[0], q1 = rp[1], q2 = rp[2];
        const float4 u0 = rt[0], u1 = rt[1], u2 = rt[2];
        const int4   mi = *(const int4*)(mask + k * CHUNK_RES + tid * 4);

        const float px[4] = {q0.x, q0.w, q1.z, q2.y};
        const float py[4] = {q0.y, q1.x, q1.w, q2.z};
        const float pz[4] = {q0.z, q1.y, q2.x, q2.w};
        const float tx[4] = {u0.x, u0.w, u1.z, u2.y};
        const float ty[4] = {u0.y, u1.x, u1.w, u2.z};
        const float tz[4] = {u0.z, u1.y, u2.x, u2.w};
        const float wm[4] = {mi.x ? 1.f : 0.f, mi.y ? 1.f : 0.f,
                             mi.z ? 1.f : 0.f, mi.w ? 1.f : 0.f};

        #pragma unroll
        for (int r = 0; r < 4; ++r) {
            const float vx = px[r] - pmx, vy = py[r] - pmy, vz = pz[r] - pmz;
            const float a0 = R00*vx + R01*vy + R02*vz + tmx - tx[r];
            const float a1 = R10*vx + R11*vy + R12*vz + tmy - ty[r];
            const float a2 = R20*vx + R21*vy + R22*vz + tmz - tz[r];
            const float dsq = a0*a0 + a1*a1 + a2*a2;
            tacc += wm[r] * __builtin_amdgcn_rcpf(1.0f + dsq * inv_d0sq);
        }
        __syncthreads();
    }
    tacc *= invLtf;

    float r = waveReduceSum(tacc);
    if (lane == 0) sred[wave][0] = r;
    __syncthreads();
    if (tid == 0)
        out[s] = sred[0][0] + sred[1][0] + sred[2][0] + sred[3][0];
}

extern "C" void kernel_launch(void* const* d_in, const int* in_sizes, int n_in,
                              void* d_out, int out_size, void* d_ws, size_t ws_size,
                              hipStream_t stream) {
    const float* pred = (const float*)d_in[0];
    const float* tru  = (const float*)d_in[1];
    const int*   mask = (const int*)d_in[2];
    float* out = (float*)d_out;
    (void)d_ws; (void)ws_size;
    tm_fused<<<NS, TPB, 0, stream>>>(pred, tru, mask, out);
}